// Round 7
// baseline (665.913 us; speedup 1.0000x reference)
//
#include <hip/hip_runtime.h>
#include <hip/hip_bf16.h>
#include <cstdint>
#include <cstddef>

#define EPS 1e-8f

typedef __attribute__((ext_vector_type(8))) short short8;
typedef __attribute__((ext_vector_type(4))) float floatx4;

static constexpr int Bb = 16, Nn = 1024, Dd = 256, Kk = 256;
static constexpr int M = Bb * Nn;                      // 16384
static constexpr size_t PM = (size_t)M * 256;          // 4,194,304 elements per modality plane

// d_out element offsets (f32)
static constexpr size_t OUT_Z      = 0;
static constexpr size_t OUT_ASSIGN = 2 * PM;
static constexpr size_t OUT_SIM    = 4 * PM;
static constexpr size_t OUT_SEM    = 6 * PM;

// ws byte offsets
static constexpr size_t OFF_QB  = 16777216;            // q0 bf16 2*PM
static constexpr size_t OFF_PN  = 33554432;            // pn bf16 2*64K
static constexpr size_t OFF_PNT = 33816576;            // pnt bf16
static constexpr size_t OFF_U   = 34078720;            // u f32 2*M
static constexpr size_t OFF_T   = 34209792;            // Tg 32 f32
static constexpr size_t OFF_VO  = 34209920;            // vout 2*16*256 f32 (was Sc)
static constexpr size_t OFF_CS  = 34406528;            // cs 2*16*256 f32
static constexpr size_t ZERO_OFF = OFF_T;
static constexpr size_t ZERO_SZ  = 128 + 196608 + 32768;   // covers Tg+vout gap+cs (harmless over-zero)
static constexpr int    NZ_FLOATS = (int)(ZERO_SZ / 4);

__device__ __forceinline__ unsigned short f2bf(float f) {
    unsigned int b = __float_as_uint(f);
    b += 0x7fffu + ((b >> 16) & 1u);          // RNE
    return (unsigned short)(b >> 16);
}
__device__ __forceinline__ float bf2f(unsigned short u) {
    return __uint_as_float(((unsigned int)u) << 16);
}

typedef const __attribute__((address_space(1))) unsigned int* gas_u32p;
typedef __attribute__((address_space(3))) unsigned int* las_u32p;
__device__ __forceinline__ void lds_cp16(const unsigned short* g, short* l) {
    __builtin_amdgcn_global_load_lds((gas_u32p)g, (las_u32p)l, 16, 0, 0);
}

// ---------------- proto normalize (+ fused scratch zeroing) ----------------
__global__ __launch_bounds__(64) void proto_kernel(const float* __restrict__ pr,
                                                   const float* __restrict__ ps,
                                                   unsigned short* __restrict__ pn,
                                                   unsigned short* __restrict__ pnt,
                                                   float* __restrict__ zp) {
    int gid = blockIdx.x * 64 + threadIdx.x;           // 0..32767
    for (int i = gid; i < NZ_FLOATS; i += 32768) zp[i] = 0.f;

    int row = blockIdx.x & 255;
    int mod = blockIdx.x >> 8;
    const float* p = (mod ? ps : pr) + (size_t)row * 256;
    int lane = threadIdx.x;
    float4 v = ((const float4*)p)[lane];
    float ss = v.x * v.x + v.y * v.y + v.z * v.z + v.w * v.w;
    #pragma unroll
    for (int m = 1; m < 64; m <<= 1) ss += __shfl_xor(ss, m);
    float sc = 1.0f / (sqrtf(ss) + EPS);
    ushort4 u4;
    u4.x = f2bf(v.x * sc); u4.y = f2bf(v.y * sc);
    u4.z = f2bf(v.z * sc); u4.w = f2bf(v.w * sc);
    *(ushort4*)(pn + (size_t)mod * 65536 + (size_t)row * 256 + lane * 4) = u4;
    unsigned short* pt = pnt + (size_t)mod * 65536 + row;
    pt[(size_t)(lane * 4 + 0) * 256] = u4.x;
    pt[(size_t)(lane * 4 + 1) * 256] = u4.y;
    pt[(size_t)(lane * 4 + 2) * 256] = u4.z;
    pt[(size_t)(lane * 4 + 3) * 256] = u4.w;
}

// ---------------- GEMM0 fused with prep (verified round-4 kernel, unchanged) ----------------
__global__ __launch_bounds__(256) void gemm0_fused(const float* __restrict__ fr,
                                                   const float* __restrict__ fs,
                                                   const unsigned short* __restrict__ pn,
                                                   unsigned short* __restrict__ qb,
                                                   float* __restrict__ doutf,
                                                   float* __restrict__ Tg) {
    __shared__ __align__(16) char smem[81920];
    short* Afull = (short*)smem;             // 65536 B
    short* Bl    = (short*)(smem + 65536);   // 16384 B (per-kh)

    int bx = blockIdx.x, by = blockIdx.y, mod = blockIdx.z;
    int t = threadIdx.x, lane = t & 63, wv = t >> 6;
    int wrow = (wv >> 1) * 64, wcol = (wv & 1) * 64;
    int g = lane >> 4, ml = lane & 15;

    const float* F0 = (mod ? fs : fr) + (size_t)by * 128 * 256;
    const unsigned short* B0 = pn + (size_t)mod * 65536 + (size_t)bx * 128 * 256;

    for (int bs = 0; bs < 4; bs++) {
        int rbase = wv * 32 + bs * 8;
        float4 vv[8];
        #pragma unroll
        for (int i = 0; i < 8; i++)
            vv[i] = ((const float4*)(F0 + (size_t)(rbase + i) * 256))[lane];
        #pragma unroll
        for (int i = 0; i < 8; i++) {
            float ss = vv[i].x * vv[i].x + vv[i].y * vv[i].y
                     + vv[i].z * vv[i].z + vv[i].w * vv[i].w;
            #pragma unroll
            for (int m = 1; m < 64; m <<= 1) ss += __shfl_xor(ss, m);
            float sc = 1.0f / (sqrtf(ss) + EPS);
            ushort4 u4;
            u4.x = f2bf(vv[i].x * sc); u4.y = f2bf(vv[i].y * sc);
            u4.z = f2bf(vv[i].z * sc); u4.w = f2bf(vv[i].w * sc);
            int row = rbase + i;
            int off = row * 256 + (((lane >> 1) ^ (row & 7)) << 3) + ((lane & 1) << 2);
            *(ushort4*)&Afull[off] = u4;
        }
    }

    floatx4 acc[4][4];
    #pragma unroll
    for (int i = 0; i < 4; i++)
        #pragma unroll
        for (int j = 0; j < 4; j++) acc[i][j] = (floatx4){0.f, 0.f, 0.f, 0.f};

    for (int kh = 0; kh < 4; kh++) {
        #pragma unroll
        for (int i = 0; i < 4; i++) {
            int sI = i * 256 + t;
            int r = sI >> 3, cs = sI & 7;
            int cg = cs ^ (r & 7);
            size_t goff = (size_t)r * 256 + kh * 64 + cg * 8;
            lds_cp16(B0 + goff, &Bl[sI * 8]);
        }
        __syncthreads();                      // kh=0: also publishes A build
        #pragma unroll
        for (int ks = 0; ks < 2; ks++) {
            short8 af[4], bfr[4];
            int c = ks * 4 + g;
            int c8 = kh * 8 + c;
            #pragma unroll
            for (int mt = 0; mt < 4; mt++) {
                int row = wrow + mt * 16 + ml;
                af[mt] = *(const short8*)&Afull[row * 256 + ((c8 ^ (row & 7)) << 3)];
            }
            #pragma unroll
            for (int nt = 0; nt < 4; nt++) {
                int col = wcol + nt * 16 + ml;
                bfr[nt] = *(const short8*)&Bl[col * 64 + ((c ^ (col & 7)) << 3)];
            }
            #pragma unroll
            for (int mt = 0; mt < 4; mt++)
                #pragma unroll
                for (int nt = 0; nt < 4; nt++)
                    acc[mt][nt] = __builtin_amdgcn_mfma_f32_16x16x32_bf16(af[mt], bfr[nt], acc[mt][nt], 0, 0, 0);
        }
        __syncthreads();
    }

    int g4 = g << 2;
    float tsum = 0.f;
    #pragma unroll
    for (int mt = 0; mt < 4; mt++)
        #pragma unroll
        for (int nt = 0; nt < 4; nt++)
            #pragma unroll
            for (int reg = 0; reg < 4; reg++) {
                float s = acc[mt][nt][reg];
                int row = by * 128 + wrow + mt * 16 + g4 + reg;
                int col = bx * 128 + wcol + nt * 16 + ml;
                size_t idx = (size_t)row * 256 + col;
                doutf[OUT_SIM + (size_t)mod * PM + idx] = s;
                unsigned short eb = f2bf(__expf(s * 20.0f));   // exp(sim/tau), tau=0.05
                qb[(size_t)mod * PM + idx] = eb;
                tsum += bf2f(eb);
            }
    #pragma unroll
    for (int mk = 1; mk < 64; mk <<= 1) tsum += __shfl_xor(tsum, mk);
    float* tred = (float*)(smem + 65536);     // Bl dead after last sync
    if (lane == 0) tred[wv] = tsum;
    __syncthreads();
    if (t == 0) atomicAdd(&Tg[mod * 16 + (by >> 3)], tred[0] + tred[1] + tred[2] + tred[3]);
}

// ---------------- Sinkhorn passes 1..5: ONE launch, zero cross-block sync ----------------
// 32 blocks = 32 independent (mod,b) chains; 1024 threads/block (16 waves, one CU).
// q slice (512 KB) is XCD-L2-resident after pass 1. All reductions intra-block:
// phase A identical 8-lane/short8/3-shfl row-sum as verified pass_kernel; phase B
// col partials (64 rows/wave) + 16-wave LDS tree (replaces 32-block Sc atomics).
// v chain and u live in LDS across passes; final v6 + u5 exported for gemm1.
__global__ __launch_bounds__(1024) void sink5_kernel(const unsigned short* __restrict__ qbg,
                                                     float* __restrict__ u,
                                                     const float* __restrict__ Tg,
                                                     float* __restrict__ vout) {
    __shared__ float vcur[256];
    __shared__ float colsum[256];
    __shared__ float unl[1024];
    __shared__ float wsum[16][256];
    int b = blockIdx.x & 15, mod = blockIdx.x >> 4;
    int t = threadIdx.x;                       // 0..1023
    int wv = t >> 6, lane = t & 63;
    int r = t >> 3, q = t & 7;                 // 128 rows per sweep, 8 lanes per row
    const unsigned short* qbase = qbg + ((size_t)mod * M + (size_t)b * 1024) * 256;
    float u0 = 1.0f / (Tg[mod * 16 + b] + EPS);

    for (int pass = 1; pass <= 5; pass++) {
        // ---- v update (same chain values as the verified per-launch recompute) ----
        if (t < 256) {
            if (pass == 1) {
                vcur[t] = 1.0f;
            } else {
                float v = vcur[t];
                vcur[t] = v * (1.0f / 256.0f) / (v * colsum[t] + EPS);
            }
        }
        __syncthreads();

        // ---- phase A: row sums (8 lanes/row; 8 sweeps x 128 rows) ----
        const float4* v4 = (const float4*)(vcur + q * 32);
        #pragma unroll
        for (int s = 0; s < 8; s++) {
            int rr = s * 128 + r;
            const short8* q8 = (const short8*)(qbase + (size_t)rr * 256 + q * 32);
            float sr = 0.f;
            #pragma unroll
            for (int i = 0; i < 4; i++) {
                short8 qv = q8[i];
                float4 va = v4[2 * i], vb = v4[2 * i + 1];
                sr += bf2f((unsigned short)qv[0]) * va.x + bf2f((unsigned short)qv[1]) * va.y
                    + bf2f((unsigned short)qv[2]) * va.z + bf2f((unsigned short)qv[3]) * va.w
                    + bf2f((unsigned short)qv[4]) * vb.x + bf2f((unsigned short)qv[5]) * vb.y
                    + bf2f((unsigned short)qv[6]) * vb.z + bf2f((unsigned short)qv[7]) * vb.w;
            }
            sr += __shfl_xor(sr, 1);
            sr += __shfl_xor(sr, 2);
            sr += __shfl_xor(sr, 4);
            float up = (pass == 1) ? u0 : unl[rr];   // 8 lanes read (lockstep) before q==0 write
            float un = up * (1.0f / 1024.0f) / (up * sr + EPS);
            if (q == 0) {
                unl[rr] = un;
                if (pass == 5) u[(size_t)mod * M + (size_t)b * 1024 + rr] = un;
            }
        }
        __syncthreads();

        // ---- phase B: col partials, wave wv owns rows wv*64..+63 ----
        float c0 = 0.f, c1 = 0.f, c2 = 0.f, c3 = 0.f;
        for (int k = 0; k < 64; k++) {
            int rr = wv * 64 + k;
            float unr = unl[rr];
            ushort4 qv = *(const ushort4*)(qbase + (size_t)rr * 256 + lane * 4);
            c0 += bf2f(qv.x) * unr;
            c1 += bf2f(qv.y) * unr;
            c2 += bf2f(qv.z) * unr;
            c3 += bf2f(qv.w) * unr;
        }
        *(float4*)&wsum[wv][lane * 4] = make_float4(c0, c1, c2, c3);
        __syncthreads();
        if (t < 256) {
            float s = 0.f;
            #pragma unroll
            for (int w = 0; w < 16; w++) s += wsum[w][t];
            colsum[t] = s;
        }
        __syncthreads();
    }

    // ---- export v6 for gemm1 phase 0 ----
    if (t < 256) {
        float v = vcur[t];
        vout[((size_t)mod * 16 + b) * 256 + t] = v * (1.0f / 256.0f) / (v * colsum[t] + EPS);
    }
}

// ---------------- GEMM1 fused with pass 6 (round-4 verified; phase 0 now loads v6) ----------------
__global__ __launch_bounds__(256) void gemm1_fused(const unsigned short* __restrict__ qbg,
                                                   const unsigned short* __restrict__ pnt,
                                                   const float* __restrict__ u,
                                                   const float* __restrict__ vout,
                                                   float* __restrict__ cs,
                                                   float* __restrict__ doutf) {
    __shared__ __align__(16) char smem[81920];
    short* Afull = (short*)smem;                     // 65536 B
    short* Bl    = (short*)(smem + 65536);           // 16384 B (phase 3)
    float* vl    = (float*)(smem + 65536);           // overlay: 256 f32 (build)
    float* unl   = (float*)(smem + 65536 + 1024);    // overlay: 128 f32
    float* wsum  = (float*)(smem + 65536 + 2048);    // overlay: 4*256 f32

    int bx = blockIdx.x, by = blockIdx.y, mod = blockIdx.z;
    int b = by >> 3;
    int t = threadIdx.x, lane = t & 63, wv = t >> 6;
    int wrow = (wv >> 1) * 64, wcol = (wv & 1) * 64;
    int g = lane >> 4, ml = lane & 15;
    int r = t >> 3, q = t & 7;
    size_t rowg0 = (size_t)by * 128;

    // ---- phase 0: load v6 (computed by sink5) ----
    vl[t] = vout[((size_t)mod * 16 + b) * 256 + t];
    __syncthreads();

    // ---- phase 1: sr -> un per row (4 sweeps x 32 rows) ----
    const float* vb0 = vl + q * 32;
    for (int s = 0; s < 4; s++) {
        int rl = s * 32 + r;
        size_t rowg = rowg0 + rl;
        const short8* q8 = (const short8*)(qbg + ((size_t)mod * PM + rowg * 256) + q * 32);
        float sr = 0.f;
        #pragma unroll
        for (int i = 0; i < 4; i++) {
            short8 qv = q8[i];
            float4 va = *(const float4*)(vb0 + i * 8);
            float4 vb = *(const float4*)(vb0 + i * 8 + 4);
            sr += bf2f((unsigned short)qv[0]) * va.x + bf2f((unsigned short)qv[1]) * va.y
                + bf2f((unsigned short)qv[2]) * va.z + bf2f((unsigned short)qv[3]) * va.w
                + bf2f((unsigned short)qv[4]) * vb.x + bf2f((unsigned short)qv[5]) * vb.y
                + bf2f((unsigned short)qv[6]) * vb.z + bf2f((unsigned short)qv[7]) * vb.w;
        }
        sr += __shfl_xor(sr, 1);
        sr += __shfl_xor(sr, 2);
        sr += __shfl_xor(sr, 4);
        float up = u[(size_t)mod * M + rowg];
        float un = up / (up * sr + EPS);               // pass-6 formula
        if (q == 0) unl[rl] = un;
    }
    __syncthreads();

    // ---- phase 2: a = q*un*v -> assign (bx==0), swizzled bf16 A, cs partials ----
    {
        float c0 = 0.f, c1 = 0.f, c2 = 0.f, c3 = 0.f;
        float4 vv = *(const float4*)(vl + lane * 4);
        float* aout = doutf + OUT_ASSIGN + (size_t)mod * PM;
        for (int s = 0; s < 4; s++) {
            #pragma unroll
            for (int k = 0; k < 8; k++) {
                int rl = s * 32 + wv * 8 + k;
                size_t rowg = rowg0 + rl;
                float unr = unl[rl];
                ushort4 qv = *(const ushort4*)(qbg + ((size_t)mod * PM + rowg * 256) + lane * 4);
                float4 a = make_float4(bf2f(qv.x) * unr * vv.x, bf2f(qv.y) * unr * vv.y,
                                       bf2f(qv.z) * unr * vv.z, bf2f(qv.w) * unr * vv.w);
                if (bx == 0) *(float4*)(aout + rowg * 256 + lane * 4) = a;
                ushort4 o;
                o.x = f2bf(a.x); o.y = f2bf(a.y); o.z = f2bf(a.z); o.w = f2bf(a.w);
                int off = rl * 256 + (((lane >> 1) ^ (rl & 7)) << 3) + ((lane & 1) << 2);
                *(ushort4*)&Afull[off] = o;
                c0 += a.x; c1 += a.y; c2 += a.z; c3 += a.w;
            }
        }
        *(float4*)&wsum[wv * 256 + lane * 4] = make_float4(c0, c1, c2, c3);
    }
    __syncthreads();
    if (bx == 0 && t < 256) {
        float ssum = wsum[0 * 256 + t] + wsum[1 * 256 + t] + wsum[2 * 256 + t] + wsum[3 * 256 + t];
        atomicAdd(&cs[((size_t)mod * 16 + b) * 256 + t], ssum);
    }
    __syncthreads();                                   // wsum reads done before Bl staging

    // ---- phase 3: MFMA vs pnt ----
    const unsigned short* B0 = pnt + (size_t)mod * 65536 + (size_t)bx * 128 * 256;
    floatx4 acc[4][4];
    #pragma unroll
    for (int i = 0; i < 4; i++)
        #pragma unroll
        for (int j = 0; j < 4; j++) acc[i][j] = (floatx4){0.f, 0.f, 0.f, 0.f};

    for (int kh = 0; kh < 4; kh++) {
        #pragma unroll
        for (int i = 0; i < 4; i++) {
            int sI = i * 256 + t;
            int rr = sI >> 3, cc = sI & 7;
            int cg = cc ^ (rr & 7);
            size_t goff = (size_t)rr * 256 + kh * 64 + cg * 8;
            lds_cp16(B0 + goff, &Bl[sI * 8]);
        }
        __syncthreads();
        #pragma unroll
        for (int ks = 0; ks < 2; ks++) {
            short8 af[4], bfr[4];
            int c = ks * 4 + g;
            int c8 = kh * 8 + c;
            #pragma unroll
            for (int mt = 0; mt < 4; mt++) {
                int row = wrow + mt * 16 + ml;
                af[mt] = *(const short8*)&Afull[row * 256 + ((c8 ^ (row & 7)) << 3)];
            }
            #pragma unroll
            for (int nt = 0; nt < 4; nt++) {
                int col = wcol + nt * 16 + ml;
                bfr[nt] = *(const short8*)&Bl[col * 64 + ((c ^ (col & 7)) << 3)];
            }
            #pragma unroll
            for (int mt = 0; mt < 4; mt++)
                #pragma unroll
                for (int nt = 0; nt < 4; nt++)
                    acc[mt][nt] = __builtin_amdgcn_mfma_f32_16x16x32_bf16(af[mt], bfr[nt], acc[mt][nt], 0, 0, 0);
        }
        __syncthreads();
    }

    int g4 = g << 2;
    float* dst = doutf + OUT_Z + (size_t)mod * PM;
    #pragma unroll
    for (int mt = 0; mt < 4; mt++)
        #pragma unroll
        for (int nt = 0; nt < 4; nt++)
            #pragma unroll
            for (int reg = 0; reg < 4; reg++) {
                int row = by * 128 + wrow + mt * 16 + g4 + reg;
                int col = bx * 128 + wcol + nt * 16 + ml;
                dst[(size_t)row * 256 + col] = acc[mt][nt][reg];
            }
}

// ---------------- sem consistency scalar ----------------
__global__ __launch_bounds__(256) void sem_kernel(const float* __restrict__ cs,
                                                  float* __restrict__ doutf) {
    int t = threadIdx.x;
    float s = 0.f;
    #pragma unroll
    for (int b = 0; b < 16; b++)
        s += cs[b * 256 + t] * cs[4096 + b * 256 + t];
    #pragma unroll
    for (int mk = 1; mk < 64; mk <<= 1) s += __shfl_xor(s, mk);
    __shared__ float red[4];
    if ((t & 63) == 0) red[t >> 6] = s;
    __syncthreads();
    if (t == 0) {
        float tot = red[0] + red[1] + red[2] + red[3];
        float mv = tot / 16777216.0f;           // B*N*N
        mv = fminf(fmaxf(mv, 0.f), 1.f);
        doutf[OUT_SEM] = 1.0f - mv;
    }
}

extern "C" void kernel_launch(void* const* d_in, const int* in_sizes, int n_in,
                              void* d_out, int out_size, void* d_ws, size_t ws_size,
                              hipStream_t stream) {
    const float* f_rgb = (const float*)d_in[0];
    const float* f_sn  = (const float*)d_in[1];
    const float* p_rgb = (const float*)d_in[2];
    const float* p_sn  = (const float*)d_in[3];
    char* ws = (char*)d_ws;
    unsigned short* qb   = (unsigned short*)(ws + OFF_QB);
    unsigned short* pn   = (unsigned short*)(ws + OFF_PN);
    unsigned short* pnt  = (unsigned short*)(ws + OFF_PNT);
    float* u             = (float*)(ws + OFF_U);
    float* Tg            = (float*)(ws + OFF_T);
    float* vout          = (float*)(ws + OFF_VO);
    float* cs            = (float*)(ws + OFF_CS);
    float* doutf         = (float*)d_out;

    proto_kernel<<<dim3(512), 64, 0, stream>>>(p_rgb, p_sn, pn, pnt, (float*)(ws + ZERO_OFF));
    gemm0_fused<<<dim3(2, 128, 2), 256, 0, stream>>>(f_rgb, f_sn, pn, qb, doutf, Tg);
    sink5_kernel<<<dim3(32), 1024, 0, stream>>>(qb, u, Tg, vout);
    gemm1_fused<<<dim3(2, 128, 2), 256, 0, stream>>>(qb, pnt, u, vout, cs, doutf);
    sem_kernel<<<1, 256, 0, stream>>>(cs, doutf);
}

// Round 8
// 199.075 us; speedup vs baseline: 3.3450x; 3.3450x over previous
//
#include <hip/hip_runtime.h>
#include <hip/hip_bf16.h>
#include <cstdint>
#include <cstddef>

#define EPS 1e-8f

typedef __attribute__((ext_vector_type(8))) short short8;
typedef __attribute__((ext_vector_type(4))) float floatx4;

static constexpr int Bb = 16, Nn = 1024, Dd = 256, Kk = 256;
static constexpr int M = Bb * Nn;                      // 16384
static constexpr size_t PM = (size_t)M * 256;          // 4,194,304 elements per modality plane

// d_out element offsets (f32)
static constexpr size_t OUT_Z      = 0;
static constexpr size_t OUT_ASSIGN = 2 * PM;
static constexpr size_t OUT_SIM    = 4 * PM;
static constexpr size_t OUT_SEM    = 6 * PM;

// ws byte offsets
static constexpr size_t OFF_QB  = 16777216;            // q0 bf16 2*PM
static constexpr size_t OFF_PN  = 33554432;            // pn bf16 2*64K
static constexpr size_t OFF_PNT = 33816576;            // pnt bf16
static constexpr size_t OFF_U   = 34078720;            // u f32 2*M
static constexpr size_t OFF_T   = 34209792;            // Tg 32 f32
static constexpr size_t OFF_SC  = 34209920;            // Sc 2*6*16*256 f32
static constexpr size_t OFF_CS  = 34406528;            // cs 2*16*256 f32
static constexpr size_t ZERO_OFF = OFF_T;
static constexpr size_t ZERO_SZ  = 128 + 196608 + 32768;
static constexpr int    NZ_FLOATS = (int)(ZERO_SZ / 4);

__device__ __forceinline__ unsigned short f2bf(float f) {
    unsigned int b = __float_as_uint(f);
    b += 0x7fffu + ((b >> 16) & 1u);          // RNE
    return (unsigned short)(b >> 16);
}
__device__ __forceinline__ float bf2f(unsigned short u) {
    return __uint_as_float(((unsigned int)u) << 16);
}

typedef const __attribute__((address_space(1))) unsigned int* gas_u32p;
typedef __attribute__((address_space(3))) unsigned int* las_u32p;
__device__ __forceinline__ void lds_cp16(const unsigned short* g, short* l) {
    __builtin_amdgcn_global_load_lds((gas_u32p)g, (las_u32p)l, 16, 0, 0);
}

// ---------------- proto normalize (+ fused scratch zeroing) ----------------
__global__ __launch_bounds__(64) void proto_kernel(const float* __restrict__ pr,
                                                   const float* __restrict__ ps,
                                                   unsigned short* __restrict__ pn,
                                                   unsigned short* __restrict__ pnt,
                                                   float* __restrict__ zp) {
    int gid = blockIdx.x * 64 + threadIdx.x;           // 0..32767
    for (int i = gid; i < NZ_FLOATS; i += 32768) zp[i] = 0.f;

    int row = blockIdx.x & 255;
    int mod = blockIdx.x >> 8;
    const float* p = (mod ? ps : pr) + (size_t)row * 256;
    int lane = threadIdx.x;
    float4 v = ((const float4*)p)[lane];
    float ss = v.x * v.x + v.y * v.y + v.z * v.z + v.w * v.w;
    #pragma unroll
    for (int m = 1; m < 64; m <<= 1) ss += __shfl_xor(ss, m);
    float sc = 1.0f / (sqrtf(ss) + EPS);
    ushort4 u4;
    u4.x = f2bf(v.x * sc); u4.y = f2bf(v.y * sc);
    u4.z = f2bf(v.z * sc); u4.w = f2bf(v.w * sc);
    *(ushort4*)(pn + (size_t)mod * 65536 + (size_t)row * 256 + lane * 4) = u4;
    unsigned short* pt = pnt + (size_t)mod * 65536 + row;
    pt[(size_t)(lane * 4 + 0) * 256] = u4.x;
    pt[(size_t)(lane * 4 + 1) * 256] = u4.y;
    pt[(size_t)(lane * 4 + 2) * 256] = u4.z;
    pt[(size_t)(lane * 4 + 3) * 256] = u4.w;
}

// ---------------- GEMM0 fused with prep (verified round-4 kernel, unchanged) ----------------
__global__ __launch_bounds__(256) void gemm0_fused(const float* __restrict__ fr,
                                                   const float* __restrict__ fs,
                                                   const unsigned short* __restrict__ pn,
                                                   unsigned short* __restrict__ qb,
                                                   float* __restrict__ doutf,
                                                   float* __restrict__ Tg) {
    __shared__ __align__(16) char smem[81920];
    short* Afull = (short*)smem;             // 65536 B
    short* Bl    = (short*)(smem + 65536);   // 16384 B (per-kh)

    int bx = blockIdx.x, by = blockIdx.y, mod = blockIdx.z;
    int t = threadIdx.x, lane = t & 63, wv = t >> 6;
    int wrow = (wv >> 1) * 64, wcol = (wv & 1) * 64;
    int g = lane >> 4, ml = lane & 15;

    const float* F0 = (mod ? fs : fr) + (size_t)by * 128 * 256;
    const unsigned short* B0 = pn + (size_t)mod * 65536 + (size_t)bx * 128 * 256;

    for (int bs = 0; bs < 4; bs++) {
        int rbase = wv * 32 + bs * 8;
        float4 vv[8];
        #pragma unroll
        for (int i = 0; i < 8; i++)
            vv[i] = ((const float4*)(F0 + (size_t)(rbase + i) * 256))[lane];
        #pragma unroll
        for (int i = 0; i < 8; i++) {
            float ss = vv[i].x * vv[i].x + vv[i].y * vv[i].y
                     + vv[i].z * vv[i].z + vv[i].w * vv[i].w;
            #pragma unroll
            for (int m = 1; m < 64; m <<= 1) ss += __shfl_xor(ss, m);
            float sc = 1.0f / (sqrtf(ss) + EPS);
            ushort4 u4;
            u4.x = f2bf(vv[i].x * sc); u4.y = f2bf(vv[i].y * sc);
            u4.z = f2bf(vv[i].z * sc); u4.w = f2bf(vv[i].w * sc);
            int row = rbase + i;
            int off = row * 256 + (((lane >> 1) ^ (row & 7)) << 3) + ((lane & 1) << 2);
            *(ushort4*)&Afull[off] = u4;
        }
    }

    floatx4 acc[4][4];
    #pragma unroll
    for (int i = 0; i < 4; i++)
        #pragma unroll
        for (int j = 0; j < 4; j++) acc[i][j] = (floatx4){0.f, 0.f, 0.f, 0.f};

    for (int kh = 0; kh < 4; kh++) {
        #pragma unroll
        for (int i = 0; i < 4; i++) {
            int sI = i * 256 + t;
            int r = sI >> 3, cs = sI & 7;
            int cg = cs ^ (r & 7);
            size_t goff = (size_t)r * 256 + kh * 64 + cg * 8;
            lds_cp16(B0 + goff, &Bl[sI * 8]);
        }
        __syncthreads();                      // kh=0: also publishes A build
        #pragma unroll
        for (int ks = 0; ks < 2; ks++) {
            short8 af[4], bfr[4];
            int c = ks * 4 + g;
            int c8 = kh * 8 + c;
            #pragma unroll
            for (int mt = 0; mt < 4; mt++) {
                int row = wrow + mt * 16 + ml;
                af[mt] = *(const short8*)&Afull[row * 256 + ((c8 ^ (row & 7)) << 3)];
            }
            #pragma unroll
            for (int nt = 0; nt < 4; nt++) {
                int col = wcol + nt * 16 + ml;
                bfr[nt] = *(const short8*)&Bl[col * 64 + ((c ^ (col & 7)) << 3)];
            }
            #pragma unroll
            for (int mt = 0; mt < 4; mt++)
                #pragma unroll
                for (int nt = 0; nt < 4; nt++)
                    acc[mt][nt] = __builtin_amdgcn_mfma_f32_16x16x32_bf16(af[mt], bfr[nt], acc[mt][nt], 0, 0, 0);
        }
        __syncthreads();
    }

    int g4 = g << 2;
    float tsum = 0.f;
    #pragma unroll
    for (int mt = 0; mt < 4; mt++)
        #pragma unroll
        for (int nt = 0; nt < 4; nt++)
            #pragma unroll
            for (int reg = 0; reg < 4; reg++) {
                float s = acc[mt][nt][reg];
                int row = by * 128 + wrow + mt * 16 + g4 + reg;
                int col = bx * 128 + wcol + nt * 16 + ml;
                size_t idx = (size_t)row * 256 + col;
                doutf[OUT_SIM + (size_t)mod * PM + idx] = s;
                unsigned short eb = f2bf(__expf(s * 20.0f));   // exp(sim/tau), tau=0.05
                qb[(size_t)mod * PM + idx] = eb;
                tsum += bf2f(eb);
            }
    #pragma unroll
    for (int mk = 1; mk < 64; mk <<= 1) tsum += __shfl_xor(tsum, mk);
    float* tred = (float*)(smem + 65536);     // Bl dead after last sync
    if (lane == 0) tred[wv] = tsum;
    __syncthreads();
    if (t == 0) atomicAdd(&Tg[mod * 16 + (by >> 3)], tred[0] + tred[1] + tred[2] + tred[3]);
}

// ---------------- Sinkhorn passes 1..5: 16-row blocks, 2048 blocks/pass ----------------
// Same dual-sweep structure as the verified round-4 kernel; only the decomposition
// changed: grid (64,16,2), 16 rows/block. Phase A: 16 lanes/row (4-level butterfly).
// Phase B: 4 rows/wave. ~5 KB LDS -> 8 blocks/CU -> fills the GPU during short passes.
__global__ __launch_bounds__(256) void pass_kernel(const unsigned short* __restrict__ qbg,
                                                   float* __restrict__ u,
                                                   const float* __restrict__ Tg,
                                                   float* __restrict__ Sc,
                                                   int pass) {
    __shared__ float vcur[256];
    __shared__ float unl[16];
    __shared__ float wsum[4][256];
    int tile = blockIdx.x, b = blockIdx.y, mod = blockIdx.z;
    int t = threadIdx.x;
    {
        float v = 1.0f;
        for (int j = 1; j < pass; j++) {
            float sc = Sc[((size_t)(mod * 6 + j) * 16 + b) * 256 + t];
            v = v * (1.0f / 256.0f) / (v * sc + EPS);
        }
        vcur[t] = v;
    }
    __syncthreads();

    // ---- phase A: row sums, 16 lanes/row over 16 rows ----
    int r = t >> 4, q = t & 15;
    size_t row = (size_t)b * 1024 + tile * 16 + r;
    const unsigned short* qrow = qbg + ((size_t)mod * M + row) * 256;
    const short8* q8 = (const short8*)(qrow + q * 16);
    const float4* v4 = (const float4*)(vcur + q * 16);
    float sr = 0.f;
    #pragma unroll
    for (int i = 0; i < 2; i++) {
        short8 qv = q8[i];
        float4 va = v4[2 * i], vb = v4[2 * i + 1];
        sr += bf2f((unsigned short)qv[0]) * va.x + bf2f((unsigned short)qv[1]) * va.y
            + bf2f((unsigned short)qv[2]) * va.z + bf2f((unsigned short)qv[3]) * va.w
            + bf2f((unsigned short)qv[4]) * vb.x + bf2f((unsigned short)qv[5]) * vb.y
            + bf2f((unsigned short)qv[6]) * vb.z + bf2f((unsigned short)qv[7]) * vb.w;
    }
    sr += __shfl_xor(sr, 1);
    sr += __shfl_xor(sr, 2);
    sr += __shfl_xor(sr, 4);
    sr += __shfl_xor(sr, 8);

    float up = (pass == 1) ? 1.0f / (Tg[mod * 16 + b] + EPS) : u[(size_t)mod * M + row];
    float un = up * (1.0f / 1024.0f) / (up * sr + EPS);
    if (q == 0) {
        u[(size_t)mod * M + row] = un;
        unl[r] = un;
    }
    __syncthreads();

    // ---- phase B: col partials, wave wv owns rows wv*4..+3 ----
    int wv = t >> 6, lane = t & 63;
    float c0 = 0.f, c1 = 0.f, c2 = 0.f, c3 = 0.f;
    size_t rowbase = (size_t)mod * M + (size_t)b * 1024 + tile * 16;
    #pragma unroll
    for (int k = 0; k < 4; k++) {
        int rr = wv * 4 + k;
        float unr = unl[rr];
        ushort4 qv = *(const ushort4*)(qbg + (rowbase + rr) * 256 + lane * 4);
        c0 += bf2f(qv.x) * unr;
        c1 += bf2f(qv.y) * unr;
        c2 += bf2f(qv.z) * unr;
        c3 += bf2f(qv.w) * unr;
    }
    *(float4*)&wsum[wv][lane * 4] = make_float4(c0, c1, c2, c3);
    __syncthreads();
    {
        float ssum = wsum[0][t] + wsum[1][t] + wsum[2][t] + wsum[3][t];
        atomicAdd(&Sc[((size_t)(mod * 6 + pass) * 16 + b) * 256 + t], ssum);
    }
}

// ---------------- GEMM1 fused with pass 6 (verified round-4 kernel, unchanged) ----------------
__global__ __launch_bounds__(256) void gemm1_fused(const unsigned short* __restrict__ qbg,
                                                   const unsigned short* __restrict__ pnt,
                                                   const float* __restrict__ u,
                                                   const float* __restrict__ Sc,
                                                   float* __restrict__ cs,
                                                   float* __restrict__ doutf) {
    __shared__ __align__(16) char smem[81920];
    short* Afull = (short*)smem;                     // 65536 B
    short* Bl    = (short*)(smem + 65536);           // 16384 B (phase 3)
    float* vl    = (float*)(smem + 65536);           // overlay: 256 f32 (build)
    float* unl   = (float*)(smem + 65536 + 1024);    // overlay: 128 f32
    float* wsum  = (float*)(smem + 65536 + 2048);    // overlay: 4*256 f32

    int bx = blockIdx.x, by = blockIdx.y, mod = blockIdx.z;
    int b = by >> 3;
    int t = threadIdx.x, lane = t & 63, wv = t >> 6;
    int wrow = (wv >> 1) * 64, wcol = (wv & 1) * 64;
    int g = lane >> 4, ml = lane & 15;
    int r = t >> 3, q = t & 7;
    size_t rowg0 = (size_t)by * 128;

    // ---- phase 0: v6 chain ----
    if (t < 256) {
        float v = 1.0f;
        #pragma unroll
        for (int j = 1; j <= 5; j++) {
            float scv = Sc[((size_t)(mod * 6 + j) * 16 + b) * 256 + t];
            v = v * (1.0f / 256.0f) / (v * scv + EPS);
        }
        vl[t] = v;
    }
    __syncthreads();

    // ---- phase 1: sr -> un per row (4 sweeps x 32 rows) ----
    const float* vb0 = vl + q * 32;
    for (int s = 0; s < 4; s++) {
        int rl = s * 32 + r;
        size_t rowg = rowg0 + rl;
        const short8* q8 = (const short8*)(qbg + ((size_t)mod * PM + rowg * 256) + q * 32);
        float sr = 0.f;
        #pragma unroll
        for (int i = 0; i < 4; i++) {
            short8 qv = q8[i];
            float4 va = *(const float4*)(vb0 + i * 8);
            float4 vb = *(const float4*)(vb0 + i * 8 + 4);
            sr += bf2f((unsigned short)qv[0]) * va.x + bf2f((unsigned short)qv[1]) * va.y
                + bf2f((unsigned short)qv[2]) * va.z + bf2f((unsigned short)qv[3]) * va.w
                + bf2f((unsigned short)qv[4]) * vb.x + bf2f((unsigned short)qv[5]) * vb.y
                + bf2f((unsigned short)qv[6]) * vb.z + bf2f((unsigned short)qv[7]) * vb.w;
        }
        sr += __shfl_xor(sr, 1);
        sr += __shfl_xor(sr, 2);
        sr += __shfl_xor(sr, 4);
        float up = u[(size_t)mod * M + rowg];
        float un = up / (up * sr + EPS);               // pass-6 formula
        if (q == 0) unl[rl] = un;
    }
    __syncthreads();

    // ---- phase 2: a = q*un*v -> assign (bx==0), swizzled bf16 A, cs partials ----
    {
        float c0 = 0.f, c1 = 0.f, c2 = 0.f, c3 = 0.f;
        float4 vv = *(const float4*)(vl + lane * 4);
        float* aout = doutf + OUT_ASSIGN + (size_t)mod * PM;
        for (int s = 0; s < 4; s++) {
            #pragma unroll
            for (int k = 0; k < 8; k++) {
                int rl = s * 32 + wv * 8 + k;
                size_t rowg = rowg0 + rl;
                float unr = unl[rl];
                ushort4 qv = *(const ushort4*)(qbg + ((size_t)mod * PM + rowg * 256) + lane * 4);
                float4 a = make_float4(bf2f(qv.x) * unr * vv.x, bf2f(qv.y) * unr * vv.y,
                                       bf2f(qv.z) * unr * vv.z, bf2f(qv.w) * unr * vv.w);
                if (bx == 0) *(float4*)(aout + rowg * 256 + lane * 4) = a;
                ushort4 o;
                o.x = f2bf(a.x); o.y = f2bf(a.y); o.z = f2bf(a.z); o.w = f2bf(a.w);
                int off = rl * 256 + (((lane >> 1) ^ (rl & 7)) << 3) + ((lane & 1) << 2);
                *(ushort4*)&Afull[off] = o;
                c0 += a.x; c1 += a.y; c2 += a.z; c3 += a.w;
            }
        }
        *(float4*)&wsum[wv * 256 + lane * 4] = make_float4(c0, c1, c2, c3);
    }
    __syncthreads();
    if (bx == 0 && t < 256) {
        float ssum = wsum[0 * 256 + t] + wsum[1 * 256 + t] + wsum[2 * 256 + t] + wsum[3 * 256 + t];
        atomicAdd(&cs[((size_t)mod * 16 + b) * 256 + t], ssum);
    }
    __syncthreads();                                   // wsum reads done before Bl staging

    // ---- phase 3: MFMA vs pnt ----
    const unsigned short* B0 = pnt + (size_t)mod * 65536 + (size_t)bx * 128 * 256;
    floatx4 acc[4][4];
    #pragma unroll
    for (int i = 0; i < 4; i++)
        #pragma unroll
        for (int j = 0; j < 4; j++) acc[i][j] = (floatx4){0.f, 0.f, 0.f, 0.f};

    for (int kh = 0; kh < 4; kh++) {
        #pragma unroll
        for (int i = 0; i < 4; i++) {
            int sI = i * 256 + t;
            int rr = sI >> 3, cc = sI & 7;
            int cg = cc ^ (rr & 7);
            size_t goff = (size_t)rr * 256 + kh * 64 + cg * 8;
            lds_cp16(B0 + goff, &Bl[sI * 8]);
        }
        __syncthreads();
        #pragma unroll
        for (int ks = 0; ks < 2; ks++) {
            short8 af[4], bfr[4];
            int c = ks * 4 + g;
            int c8 = kh * 8 + c;
            #pragma unroll
            for (int mt = 0; mt < 4; mt++) {
                int row = wrow + mt * 16 + ml;
                af[mt] = *(const short8*)&Afull[row * 256 + ((c8 ^ (row & 7)) << 3)];
            }
            #pragma unroll
            for (int nt = 0; nt < 4; nt++) {
                int col = wcol + nt * 16 + ml;
                bfr[nt] = *(const short8*)&Bl[col * 64 + ((c ^ (col & 7)) << 3)];
            }
            #pragma unroll
            for (int mt = 0; mt < 4; mt++)
                #pragma unroll
                for (int nt = 0; nt < 4; nt++)
                    acc[mt][nt] = __builtin_amdgcn_mfma_f32_16x16x32_bf16(af[mt], bfr[nt], acc[mt][nt], 0, 0, 0);
        }
        __syncthreads();
    }

    int g4 = g << 2;
    float* dst = doutf + OUT_Z + (size_t)mod * PM;
    #pragma unroll
    for (int mt = 0; mt < 4; mt++)
        #pragma unroll
        for (int nt = 0; nt < 4; nt++)
            #pragma unroll
            for (int reg = 0; reg < 4; reg++) {
                int row = by * 128 + wrow + mt * 16 + g4 + reg;
                int col = bx * 128 + wcol + nt * 16 + ml;
                dst[(size_t)row * 256 + col] = acc[mt][nt][reg];
            }
}

// ---------------- sem consistency scalar ----------------
__global__ __launch_bounds__(256) void sem_kernel(const float* __restrict__ cs,
                                                  float* __restrict__ doutf) {
    int t = threadIdx.x;
    float s = 0.f;
    #pragma unroll
    for (int b = 0; b < 16; b++)
        s += cs[b * 256 + t] * cs[4096 + b * 256 + t];
    #pragma unroll
    for (int mk = 1; mk < 64; mk <<= 1) s += __shfl_xor(s, mk);
    __shared__ float red[4];
    if ((t & 63) == 0) red[t >> 6] = s;
    __syncthreads();
    if (t == 0) {
        float tot = red[0] + red[1] + red[2] + red[3];
        float mv = tot / 16777216.0f;           // B*N*N
        mv = fminf(fmaxf(mv, 0.f), 1.f);
        doutf[OUT_SEM] = 1.0f - mv;
    }
}

extern "C" void kernel_launch(void* const* d_in, const int* in_sizes, int n_in,
                              void* d_out, int out_size, void* d_ws, size_t ws_size,
                              hipStream_t stream) {
    const float* f_rgb = (const float*)d_in[0];
    const float* f_sn  = (const float*)d_in[1];
    const float* p_rgb = (const float*)d_in[2];
    const float* p_sn  = (const float*)d_in[3];
    char* ws = (char*)d_ws;
    unsigned short* qb   = (unsigned short*)(ws + OFF_QB);
    unsigned short* pn   = (unsigned short*)(ws + OFF_PN);
    unsigned short* pnt  = (unsigned short*)(ws + OFF_PNT);
    float* u             = (float*)(ws + OFF_U);
    float* Tg            = (float*)(ws + OFF_T);
    float* Sc            = (float*)(ws + OFF_SC);
    float* cs            = (float*)(ws + OFF_CS);
    float* doutf         = (float*)d_out;

    proto_kernel<<<dim3(512), 64, 0, stream>>>(p_rgb, p_sn, pn, pnt, (float*)(ws + ZERO_OFF));
    gemm0_fused<<<dim3(2, 128, 2), 256, 0, stream>>>(f_rgb, f_sn, pn, qb, doutf, Tg);
    for (int p = 1; p <= 5; p++)
        pass_kernel<<<dim3(64, 16, 2), 256, 0, stream>>>(qb, u, Tg, Sc, p);
    gemm1_fused<<<dim3(2, 128, 2), 256, 0, stream>>>(qb, pnt, u, Sc, cs, doutf);
    sem_kernel<<<1, 256, 0, stream>>>(cs, doutf);
}